// Round 11
// baseline (1759.207 us; speedup 1.0000x reference)
//
#include <hip/hip_runtime.h>
#include <stdint.h>

// Problem constants
#define TOTAL_T 100
#define NB 256          // batch
#define NH 200          // hidden per (c,d) cell
#define NJ (NB*NH)      // 51200
#define KDIM 1024       // FS*FS
#define NEFF 600        // d*200+h per c
#define NPAD 640        // 5 tiles of 128
#define NTILES 5
#define KBLKS 32        // KDIM/32

// GEMM tiling
#define BM 128
#define BN 128
#define AST 1040        // A kg-subtile stride in halves (128*8 + 8 pad)

// Pre-split Wh limb array: [c][kb][nt][kg][row][8] halves
#define WCHUNK 4096
#define NWHALF (3 * KBLKS * NTILES * WCHUNK)

typedef _Float16 f16x8 __attribute__((ext_vector_type(8)));
typedef float    f32x4 __attribute__((ext_vector_type(4)));
typedef __attribute__((address_space(3))) uint32_t as3_u32;
typedef __attribute__((address_space(1))) uint32_t as1_u32;

// ---------------- P2: pre-split Wh into fp16 hi/mid limbs, frag-order tiles ----
__global__ __launch_bounds__(256) void presplit_wh(
    const float* __restrict__ Wh, unsigned short* __restrict__ WH,
    unsigned short* __restrict__ WM)
{
    int idx = blockIdx.x * 256 + threadIdx.x;      // over 3*640*1024
    if (idx >= 3 * NPAD * KDIM) return;
    int k = idx & (KDIM - 1);
    int n = (idx >> 10) % NPAD;
    int c = idx / (NPAD * KDIM);
    float v = 0.f;
    if (n < NEFF) v = Wh[((size_t)c * NEFF + n) * KDIM + k];
    _Float16 h = (_Float16)v;                      // RN
    float r = v - (float)h;                        // exact
    _Float16 m = (_Float16)r;                      // RN
    int kb = k >> 5, kg = (k >> 3) & 3, kj = k & 7;
    int nt = n >> 7, row = n & 127;
    size_t off = (((size_t)c * KBLKS + kb) * NTILES + nt) * WCHUNK
               + (kg * 128 + row) * 8 + kj;
    WH[off] = __builtin_bit_cast(unsigned short, h);
    WM[off] = __builtin_bit_cast(unsigned short, m);
}

// ---------------- K1: fp16 2-limb GEMM; A coop-LDS, B single-buffer LDS --------
// Occupancy-first design: LDS = 32.3 KB -> 4 blocks/CU (16 waves). Blocks are
// NOT barrier-synced with each other, so at any instant some resident block is
// in its MFMA phase while another drains its DMA — that inter-block desync is
// the latency hiding. Loop is fully uniform (clamped tail indices, no branches);
// end-of-iter wait is counted vmcnt(4): retires B[kb+1], leaves A[kb+2] in flight.

#define LOAD_A(KB)                                                              \
  {                                                                             \
    _Pragma("unroll")                                                           \
    for (int l = 0; l < 4; ++l)                                                 \
      avn[l] = *reinterpret_cast<const float4*>(                                \
          xb + (size_t)(srow + (l << 5)) * 3 * KDIM + ((KB) << 5));             \
  }

#define DMA_B(KB)                                                               \
  {                                                                             \
    const unsigned short* nbh_ = bhp + (size_t)(KB) * (NTILES * WCHUNK);        \
    const unsigned short* nbm_ = bmp + (size_t)(KB) * (NTILES * WCHUNK);        \
    _Pragma("unroll")                                                           \
    for (int i = 0; i < 2; ++i) {                                               \
      int seg = (i << 2) + w;                                                   \
      __builtin_amdgcn_global_load_lds(                                         \
          (const as1_u32*)(nbh_ + ((seg << 6) + lane) * 8),                     \
          (as3_u32*)&Bh[seg << 9], 16, 0, 0);                                   \
      __builtin_amdgcn_global_load_lds(                                         \
          (const as1_u32*)(nbm_ + ((seg << 6) + lane) * 8),                     \
          (as3_u32*)&Bm[seg << 9], 16, 0, 0);                                   \
    }                                                                           \
  }

#define SPLIT_A()                                                               \
  {                                                                             \
    _Pragma("unroll")                                                           \
    for (int l = 0; l < 4; ++l) {                                               \
      int row_ = srow + (l << 5);                                               \
      float a0 = avn[l].x, a1 = avn[l].y, a2 = avn[l].z, a3 = avn[l].w;         \
      _Float16 h0 = (_Float16)a0, h1 = (_Float16)a1,                            \
               h2 = (_Float16)a2, h3 = (_Float16)a3;                            \
      _Float16 q0 = (_Float16)(a0 - (float)h0), q1 = (_Float16)(a1 - (float)h1);\
      _Float16 q2 = (_Float16)(a2 - (float)h2), q3 = (_Float16)(a3 - (float)h3);\
      uint32_t hw0 = (uint32_t)__builtin_bit_cast(unsigned short, h0)           \
                   | ((uint32_t)__builtin_bit_cast(unsigned short, h1) << 16);  \
      uint32_t hw1 = (uint32_t)__builtin_bit_cast(unsigned short, h2)           \
                   | ((uint32_t)__builtin_bit_cast(unsigned short, h3) << 16);  \
      uint32_t mw0 = (uint32_t)__builtin_bit_cast(unsigned short, q0)           \
                   | ((uint32_t)__builtin_bit_cast(unsigned short, q1) << 16);  \
      uint32_t mw1 = (uint32_t)__builtin_bit_cast(unsigned short, q2)           \
                   | ((uint32_t)__builtin_bit_cast(unsigned short, q3) << 16);  \
      int off_ = kgw * AST + row_ * 8 + kjw;                                    \
      *reinterpret_cast<uint2*>(&Ah[off_]) = make_uint2(hw0, hw1);              \
      *reinterpret_cast<uint2*>(&Am[off_]) = make_uint2(mw0, mw1);              \
    }                                                                           \
  }

#define FRAGS()                                                                 \
  {                                                                             \
    _Pragma("unroll")                                                           \
    for (int mi = 0; mi < 4; ++mi) {                                            \
      int aoff_ = kg * AST + (mbase + (mi << 4) + lrow) * 8;                    \
      afh[mi] = *reinterpret_cast<const f16x8*>(&Ah[aoff_]);                    \
      afm[mi] = *reinterpret_cast<const f16x8*>(&Am[aoff_]);                    \
    }                                                                           \
    _Pragma("unroll")                                                           \
    for (int ni = 0; ni < 4; ++ni) {                                            \
      int boff_ = ((kg << 7) + nbase + (ni << 4) + lrow) << 3;                  \
      bfh[ni] = *reinterpret_cast<const f16x8*>(&Bh[boff_]);                    \
      bfm[ni] = *reinterpret_cast<const f16x8*>(&Bm[boff_]);                    \
    }                                                                           \
  }

#define MFMA_CL()                                                               \
  {                                                                             \
    __builtin_amdgcn_s_setprio(1);                                              \
    _Pragma("unroll")                                                           \
    for (int ni = 0; ni < 4; ++ni)                                              \
      _Pragma("unroll")                                                         \
      for (int mi = 0; mi < 4; ++mi) {                                          \
        f32x4 a_ = acc[mi][ni];                                                 \
        a_ = __builtin_amdgcn_mfma_f32_16x16x32_f16(afh[mi], bfh[ni], a_,0,0,0);\
        a_ = __builtin_amdgcn_mfma_f32_16x16x32_f16(afh[mi], bfm[ni], a_,0,0,0);\
        a_ = __builtin_amdgcn_mfma_f32_16x16x32_f16(afm[mi], bfh[ni], a_,0,0,0);\
        acc[mi][ni] = a_;                                                       \
      }                                                                         \
    __builtin_amdgcn_s_setprio(0);                                              \
  }

__global__ __launch_bounds__(256, 4) void gemm_inj_mfma(
    const float* __restrict__ x,          // chunk base
    const unsigned short* __restrict__ WH,
    const unsigned short* __restrict__ WM,
    const float* __restrict__ bh,
    float* __restrict__ inj,
    int Mc, int MBlk)
{
    __shared__ __align__(16) unsigned short Ah[4 * AST], Am[4 * AST];   // 16.6 KB
    __shared__ __align__(16) unsigned short Bh[4096], Bm[4096];         // 16 KB

    const int tid  = threadIdx.x;
    const int lane = tid & 63;
    const int w    = tid >> 6;            // 4 waves, 2x2
    const int mbase = (w >> 1) * 64;
    const int nbase = (w & 1) * 64;

    // XCD-aware bijective remap: hw id -> logical (c, mb, nt), nt FASTEST
    // (5 consecutive blocks share one 512KB A-tile -> L2 hits; B L3-resident).
    const int nblk = gridDim.x;
    const int hwid = blockIdx.x;
    const int xcd  = hwid & 7, jj = hwid >> 3;
    const int q = nblk >> 3, rr = nblk & 7;
    const int L = (xcd < rr ? xcd * (q + 1) : rr * (q + 1) + (xcd - rr) * q) + jj;
    const int c   = L / (NTILES * MBlk);
    const int rem = L - c * (NTILES * MBlk);
    const int mb  = rem / NTILES;
    const int nt  = rem - mb * NTILES;
    const int n0 = nt * BN;
    const int m0 = mb * BM;

    f32x4 acc[4][4];
#pragma unroll
    for (int i = 0; i < 4; ++i)
#pragma unroll
        for (int j = 0; j < 4; ++j) acc[i][j] = (f32x4)0.f;

    const int srow = tid >> 3;            // 0..31
    const int skq  = (tid & 7) << 2;      // 0,4,..,28 (halves)
    const int kgw  = skq >> 3;
    const int kjw  = skq & 7;
    const int kg   = lane >> 4;
    const int lrow = lane & 15;

    const unsigned short* bhp = WH + ((size_t)c * KBLKS * NTILES + nt) * WCHUNK;
    const unsigned short* bmp = WM + ((size_t)c * KBLKS * NTILES + nt) * WCHUNK;
    const float* xb = x + (size_t)m0 * 3 * KDIM + (size_t)c * KDIM + skq;

    float4 avn[4];
    f16x8 afh[4], afm[4], bfh[4], bfm[4];

    // ---- prologue: A[0] regs + B[0] DMA; split A[0]; A[1] in flight
    LOAD_A(0);                                         // vmcnt: 4
    DMA_B(0);                                          // vmcnt: 8
    asm volatile("s_waitcnt vmcnt(4)" ::: "memory");   // A[0] arrived
    __builtin_amdgcn_sched_barrier(0);
    SPLIT_A();                                         // A[0] -> LDS
    LOAD_A(1);                                         // vmcnt: 8 (B0 + A1)
    asm volatile("s_waitcnt vmcnt(4)" ::: "memory");   // B[0] landed (A1 flies)
    asm volatile("s_waitcnt lgkmcnt(0)" ::: "memory");
    __builtin_amdgcn_s_barrier();
    __builtin_amdgcn_sched_barrier(0);

    // ---- main loop, fully uniform (clamped tail indices)
    for (int kb = 0; kb < KBLKS; ++kb) {
        const int kn1 = (kb + 1 < KBLKS) ? kb + 1 : KBLKS - 1;
        const int kn2 = (kb + 2 < KBLKS) ? kb + 2 : KBLKS - 1;
        FRAGS();                                       // A[kb], B[kb] -> regs
        asm volatile("s_waitcnt lgkmcnt(0)" ::: "memory");
        __builtin_amdgcn_s_barrier();                  // all waves read LDS
        __builtin_amdgcn_sched_barrier(0);
        DMA_B(kn1);                                    // overwrite B buffer
        __builtin_amdgcn_sched_barrier(0);
        MFMA_CL();                                     // covers DMA latency
        __builtin_amdgcn_sched_barrier(0);
        SPLIT_A();                                     // avn = A[kb+1] -> LDS
        LOAD_A(kn2);                                   // next A into regs
        asm volatile("s_waitcnt vmcnt(4)" ::: "memory");  // B[kn1] done, A flies
        asm volatile("s_waitcnt lgkmcnt(0)" ::: "memory");
        __builtin_amdgcn_s_barrier();                  // publish A[kb+1], B[kn1]
        __builtin_amdgcn_sched_barrier(0);
    }

    // C layout: col = lane&15 (N), row = (lane>>4)*4 + reg (M)
#pragma unroll
    for (int ni = 0; ni < 4; ++ni) {
        int ncol = n0 + nbase + (ni << 4) + lrow;
        if (ncol >= NEFF) continue;
        int d = ncol / 200;
        int h = ncol - d * 200;
        float bias = bh[c * NEFF + ncol];
        size_t obase = (size_t)(c * 3 + d) * Mc;
#pragma unroll
        for (int mi = 0; mi < 4; ++mi) {
            int mrow = m0 + mbase + (mi << 4) + ((lane >> 4) << 2);
#pragma unroll
            for (int r = 0; r < 4; ++r)
                inj[(obase + mrow + r) * NH + h] = acc[mi][ni][r] + bias;
        }
    }
}

// K2: per-(b,h) thread owns 9 LIF cells; scan Tc steps, emit summed spikes z.
__global__ __launch_bounds__(256) void scan_z(
    const float* __restrict__ inj,  // [cd][t][j]
    float* __restrict__ z,          // [t][j]
    float* __restrict__ vhs, float* __restrict__ ihs,  // [cd][j]
    int Tc, int first)
{
    int j = blockIdx.x * 256 + threadIdx.x;
    float vh[9], ih[9];
    if (first) {
#pragma unroll
        for (int cd = 0; cd < 9; ++cd) { vh[cd] = 0.f; ih[cd] = 0.f; }
    } else {
#pragma unroll
        for (int cd = 0; cd < 9; ++cd) {
            vh[cd] = vhs[cd * NJ + j];
            ih[cd] = ihs[cd * NJ + j];
        }
    }
    float ivc[9], ivn[9];
#pragma unroll
    for (int cd = 0; cd < 9; ++cd)
        ivc[cd] = inj[(size_t)cd * Tc * NJ + j];
    if (Tc > 1) {
#pragma unroll
        for (int cd = 0; cd < 9; ++cd)
            ivn[cd] = inj[((size_t)cd * Tc + 1) * NJ + j];
    }
    for (int t = 0; t < Tc; ++t) {
        float zs = 0.f;
#pragma unroll
        for (int cd = 0; cd < 9; ++cd) {
            float iv = ivc[cd];
            ivc[cd] = ivn[cd];
            float vd = vh[cd] + 0.1f * (ih[cd] - vh[cd]);  // uses OLD ih
            ih[cd] = 0.8f * ih[cd] + iv;
            if (vd > 1.0f) { zs += 1.f; vh[cd] = 0.f; }
            else           { vh[cd] = vd; }
        }
        z[(size_t)t * NJ + j] = zs;
        if (t + 2 < Tc) {
#pragma unroll
            for (int cd = 0; cd < 9; ++cd)
                ivn[cd] = inj[((size_t)cd * Tc + t + 2) * NJ + j];
        }
    }
#pragma unroll
    for (int cd = 0; cd < 9; ++cd) {
        vhs[cd * NJ + j] = vh[cd];
        ihs[cd * NJ + j] = ih[cd];
    }
}

// K3: closed-form readout. vo[t] = 0.9^{dt+1} vo0 + (0.9^{dt+1}-0.8^{dt+1}) io0
//                                  + sum_s (0.9^{t-s}-0.8^{t-s}) u[s]
__global__ __launch_bounds__(256) void readout(
    const float* __restrict__ z,    // [t][j] chunk
    const float* __restrict__ Wo,   // [40][50]
    const float* __restrict__ bo,   // [40]
    float* __restrict__ out,        // [t][b][10]
    float* __restrict__ ios, float* __restrict__ vos,  // [b][40]
    int t0, int Tc, int first)
{
    const int b = blockIdx.x;
    const int tid = threadIdx.x;
    __shared__ float ush[TOTAL_T][40];
    __shared__ float usum[TOTAL_T][10];
    __shared__ float p9[TOTAL_T + 1], p8[TOTAL_T + 1];
    __shared__ float wsh[2000], bsh[40];
    for (int i = tid; i < 2000; i += 256) wsh[i] = Wo[i];
    if (tid < 40) bsh[tid] = bo[tid];
    if (tid == 0) {
        float a9 = 1.f, a8 = 1.f;
        for (int i = 0; i <= TOTAL_T; ++i) {
            p9[i] = a9; p8[i] = a8; a9 *= 0.9f; a8 *= 0.8f;
        }
    }
    __syncthreads();
    // phase 1: u[s][on] = bo + z . Wo
    for (int it = tid; it < Tc * 40; it += 256) {
        int s = it / 40, on = it - s * 40;
        int o = on / 10;
        const float* zr = z + (size_t)s * NJ + b * NH + o * 50;
        const float* wr = &wsh[on * 50];
        float dot = bsh[on];
#pragma unroll
        for (int k = 0; k < 50; ++k) dot += zr[k] * wr[k];
        ush[s][on] = dot;
    }
    __syncthreads();
    // phase 1.5: collapse o (readout is linear)
    for (int it = tid; it < Tc * 10; it += 256) {
        int s = it / 10, n = it - s * 10;
        usum[s][n] = ush[s][n] + ush[s][10 + n] + ush[s][20 + n] + ush[s][30 + n];
    }
    __syncthreads();
    // phase 2: out[t][n]
    for (int it = tid; it < Tc * 10; it += 256) {
        int t = it / 10, n = it - t * 10;
        float a = 0.f;
        for (int s = 0; s <= t; ++s)
            a += (p9[t - s] - p8[t - s]) * usum[s][n];
        if (!first) {
#pragma unroll
            for (int o = 0; o < 4; ++o) {
                int on = o * 10 + n;
                a += p9[t + 1] * vos[b * 40 + on]
                   + (p9[t + 1] - p8[t + 1]) * ios[b * 40 + on];
            }
        }
        out[((size_t)(t0 + t) * NB + b) * 10 + n] = a;
    }
    __syncthreads();
    // phase 3: analytic state handoff
    if (tid < 40) {
        int on = tid;
        float io0 = 0.f, vo0 = 0.f;
        if (!first) { io0 = ios[b * 40 + on]; vo0 = vos[b * 40 + on]; }
        float sio = 0.f, svo = 0.f;
        for (int s = 0; s < Tc; ++s) {
            sio += p8[Tc - 1 - s] * ush[s][on];
            svo += (p9[Tc - 1 - s] - p8[Tc - 1 - s]) * ush[s][on];
        }
        ios[b * 40 + on] = p8[Tc] * io0 + sio;
        vos[b * 40 + on] = p9[Tc] * vo0 + (p9[Tc] - p8[Tc]) * io0 + svo;
    }
}

extern "C" void kernel_launch(void* const* d_in, const int* in_sizes, int n_in,
                              void* d_out, int out_size, void* d_ws, size_t ws_size,
                              hipStream_t stream) {
    (void)in_sizes; (void)n_in; (void)out_size;
    const float* x  = (const float*)d_in[0];
    const float* Wh = (const float*)d_in[1];
    const float* bh = (const float*)d_in[2];
    const float* Wo = (const float*)d_in[3];
    const float* bo = (const float*)d_in[4];
    float* out = (float*)d_out;

    // ws layout: [vh][ih][io][vo][WH limbs][WM limbs][inj chunk][z chunk]
    float* vhs  = (float*)d_ws;          // 9*NJ
    float* ihs  = vhs + 9 * NJ;          // 9*NJ
    float* ios  = ihs + 9 * NJ;          // NB*40
    float* vos  = ios + NB * 40;         // NB*40
    unsigned short* WHl = (unsigned short*)(vos + NB * 40);
    unsigned short* WMl = WHl + NWHALF;
    float* inj  = (float*)(WMl + NWHALF);

    size_t fixed = ((size_t)9 * NJ * 2 + (size_t)NB * 40 * 2) * 4
                 + (size_t)NWHALF * 2 * 2;
    size_t per_t = (size_t)NB * (9 * NH * 4 + NH * 4);   // inj + z
    int Tc = 1;
    for (int t = TOTAL_T; t >= 1; --t) {
        if (fixed + (size_t)t * per_t <= ws_size) { Tc = t; break; }
    }

    presplit_wh<<<(3 * NPAD * KDIM + 255) / 256, 256, 0, stream>>>(Wh, WHl, WMl);

    for (int t0 = 0; t0 < TOTAL_T; t0 += Tc) {
        int tc = (TOTAL_T - t0 < Tc) ? (TOTAL_T - t0) : Tc;
        int Mc = tc * NB;
        int MBlk = Mc / BM;
        float* zbuf = inj + (size_t)9 * Mc * NH;
        gemm_inj_mfma<<<NTILES * MBlk * 3, 256, 0, stream>>>(
            x + (size_t)t0 * NB * 3 * KDIM, WHl, WMl, bh, inj, Mc, MBlk);
        scan_z<<<NJ / 256, 256, 0, stream>>>(inj, zbuf, vhs, ihs, tc, t0 == 0);
        readout<<<NB, 256, 0, stream>>>(
            zbuf, Wo, bo, out, ios, vos, t0, tc, t0 == 0);
    }
}

// Round 12
// 457.523 us; speedup vs baseline: 3.8451x; 3.8451x over previous
//
#include <hip/hip_runtime.h>
#include <stdint.h>

// Problem constants
#define TOTAL_T 100
#define NB 256          // batch
#define NH 200          // hidden per (c,d) cell
#define NJ (NB*NH)      // 51200
#define KDIM 1024       // FS*FS
#define NEFF 600        // d*200+h per c
#define NPAD 640        // 5 tiles of 128
#define NTILES 5
#define KBLKS 32        // KDIM/32

// GEMM tiling
#define BM 128
#define BN 128
#define AST 1040        // A kg-subtile stride in halves (128*8 + 8 pad)

// Pre-split Wh limb array: [c][kb][nt][kg][row][8] halves
#define WCHUNK 4096
#define NWHALF (3 * KBLKS * NTILES * WCHUNK)

typedef _Float16 f16x8 __attribute__((ext_vector_type(8)));
typedef float    f32x4 __attribute__((ext_vector_type(4)));
typedef __attribute__((address_space(3))) uint32_t as3_u32;
typedef __attribute__((address_space(1))) uint32_t as1_u32;

// ---------------- P2: pre-split Wh into fp16 hi/mid limbs, frag-order tiles ----
__global__ __launch_bounds__(256) void presplit_wh(
    const float* __restrict__ Wh, unsigned short* __restrict__ WH,
    unsigned short* __restrict__ WM)
{
    int idx = blockIdx.x * 256 + threadIdx.x;      // over 3*640*1024
    if (idx >= 3 * NPAD * KDIM) return;
    int k = idx & (KDIM - 1);
    int n = (idx >> 10) % NPAD;
    int c = idx / (NPAD * KDIM);
    float v = 0.f;
    if (n < NEFF) v = Wh[((size_t)c * NEFF + n) * KDIM + k];
    _Float16 h = (_Float16)v;                      // RN
    float r = v - (float)h;                        // exact
    _Float16 m = (_Float16)r;                      // RN
    int kb = k >> 5, kg = (k >> 3) & 3, kj = k & 7;
    int nt = n >> 7, row = n & 127;
    size_t off = (((size_t)c * KBLKS + kb) * NTILES + nt) * WCHUNK
               + (kg * 128 + row) * 8 + kj;
    WH[off] = __builtin_bit_cast(unsigned short, h);
    WM[off] = __builtin_bit_cast(unsigned short, m);
}

// ---------------- K1: fp16 2-limb GEMM; A coop-LDS, B single-buffer LDS --------
// Occupancy-first design: LDS = 32.3 KB and natural VGPR ~108 -> 4 blocks/CU
// (16 waves) with NO register cap (r11's (256,4) forced VGPR=64 -> 4.15 GB of
// scratch spill; (256,2) leaves the allocator free). Blocks are not
// barrier-synced with each other, so at any instant some resident block is in
// its MFMA phase while another drains its DMA — inter-block desync is the
// latency hiding. Loop fully uniform (clamped tail indices); end-of-iter wait
// is counted vmcnt(4): retires B[kb+1], leaves A[kb+2] in flight.

#define LOAD_A(KB)                                                              \
  {                                                                             \
    _Pragma("unroll")                                                           \
    for (int l = 0; l < 4; ++l)                                                 \
      avn[l] = *reinterpret_cast<const float4*>(                                \
          xb + (size_t)(srow + (l << 5)) * 3 * KDIM + ((KB) << 5));             \
  }

#define DMA_B(KB)                                                               \
  {                                                                             \
    const unsigned short* nbh_ = bhp + (size_t)(KB) * (NTILES * WCHUNK);        \
    const unsigned short* nbm_ = bmp + (size_t)(KB) * (NTILES * WCHUNK);        \
    _Pragma("unroll")                                                           \
    for (int i = 0; i < 2; ++i) {                                               \
      int seg = (i << 2) + w;                                                   \
      __builtin_amdgcn_global_load_lds(                                         \
          (const as1_u32*)(nbh_ + ((seg << 6) + lane) * 8),                     \
          (as3_u32*)&Bh[seg << 9], 16, 0, 0);                                   \
      __builtin_amdgcn_global_load_lds(                                         \
          (const as1_u32*)(nbm_ + ((seg << 6) + lane) * 8),                     \
          (as3_u32*)&Bm[seg << 9], 16, 0, 0);                                   \
    }                                                                           \
  }

#define SPLIT_A()                                                               \
  {                                                                             \
    _Pragma("unroll")                                                           \
    for (int l = 0; l < 4; ++l) {                                               \
      int row_ = srow + (l << 5);                                               \
      float a0 = avn[l].x, a1 = avn[l].y, a2 = avn[l].z, a3 = avn[l].w;         \
      _Float16 h0 = (_Float16)a0, h1 = (_Float16)a1,                            \
               h2 = (_Float16)a2, h3 = (_Float16)a3;                            \
      _Float16 q0 = (_Float16)(a0 - (float)h0), q1 = (_Float16)(a1 - (float)h1);\
      _Float16 q2 = (_Float16)(a2 - (float)h2), q3 = (_Float16)(a3 - (float)h3);\
      uint32_t hw0 = (uint32_t)__builtin_bit_cast(unsigned short, h0)           \
                   | ((uint32_t)__builtin_bit_cast(unsigned short, h1) << 16);  \
      uint32_t hw1 = (uint32_t)__builtin_bit_cast(unsigned short, h2)           \
                   | ((uint32_t)__builtin_bit_cast(unsigned short, h3) << 16);  \
      uint32_t mw0 = (uint32_t)__builtin_bit_cast(unsigned short, q0)           \
                   | ((uint32_t)__builtin_bit_cast(unsigned short, q1) << 16);  \
      uint32_t mw1 = (uint32_t)__builtin_bit_cast(unsigned short, q2)           \
                   | ((uint32_t)__builtin_bit_cast(unsigned short, q3) << 16);  \
      int off_ = kgw * AST + row_ * 8 + kjw;                                    \
      *reinterpret_cast<uint2*>(&Ah[off_]) = make_uint2(hw0, hw1);              \
      *reinterpret_cast<uint2*>(&Am[off_]) = make_uint2(mw0, mw1);              \
    }                                                                           \
  }

#define FRAGS()                                                                 \
  {                                                                             \
    _Pragma("unroll")                                                           \
    for (int mi = 0; mi < 4; ++mi) {                                            \
      int aoff_ = kg * AST + (mbase + (mi << 4) + lrow) * 8;                    \
      afh[mi] = *reinterpret_cast<const f16x8*>(&Ah[aoff_]);                    \
      afm[mi] = *reinterpret_cast<const f16x8*>(&Am[aoff_]);                    \
    }                                                                           \
    _Pragma("unroll")                                                           \
    for (int ni = 0; ni < 4; ++ni) {                                            \
      int boff_ = ((kg << 7) + nbase + (ni << 4) + lrow) << 3;                  \
      bfh[ni] = *reinterpret_cast<const f16x8*>(&Bh[boff_]);                    \
      bfm[ni] = *reinterpret_cast<const f16x8*>(&Bm[boff_]);                    \
    }                                                                           \
  }

#define MFMA_CL()                                                               \
  {                                                                             \
    __builtin_amdgcn_s_setprio(1);                                              \
    _Pragma("unroll")                                                           \
    for (int ni = 0; ni < 4; ++ni)                                              \
      _Pragma("unroll")                                                         \
      for (int mi = 0; mi < 4; ++mi) {                                          \
        f32x4 a_ = acc[mi][ni];                                                 \
        a_ = __builtin_amdgcn_mfma_f32_16x16x32_f16(afh[mi], bfh[ni], a_,0,0,0);\
        a_ = __builtin_amdgcn_mfma_f32_16x16x32_f16(afh[mi], bfm[ni], a_,0,0,0);\
        a_ = __builtin_amdgcn_mfma_f32_16x16x32_f16(afm[mi], bfh[ni], a_,0,0,0);\
        acc[mi][ni] = a_;                                                       \
      }                                                                         \
    __builtin_amdgcn_s_setprio(0);                                              \
  }

__global__ __launch_bounds__(256, 2) void gemm_inj_mfma(
    const float* __restrict__ x,          // chunk base
    const unsigned short* __restrict__ WH,
    const unsigned short* __restrict__ WM,
    const float* __restrict__ bh,
    float* __restrict__ inj,
    int Mc, int MBlk)
{
    __shared__ __align__(16) unsigned short Ah[4 * AST], Am[4 * AST];   // 16.6 KB
    __shared__ __align__(16) unsigned short Bh[4096], Bm[4096];         // 16 KB

    const int tid  = threadIdx.x;
    const int lane = tid & 63;
    const int w    = tid >> 6;            // 4 waves, 2x2
    const int mbase = (w >> 1) * 64;
    const int nbase = (w & 1) * 64;

    // XCD-aware bijective remap: hw id -> logical (c, mb, nt), nt FASTEST
    // (5 consecutive blocks share one 512KB A-tile -> L2 hits; B L3-resident).
    const int nblk = gridDim.x;
    const int hwid = blockIdx.x;
    const int xcd  = hwid & 7, jj = hwid >> 3;
    const int q = nblk >> 3, rr = nblk & 7;
    const int L = (xcd < rr ? xcd * (q + 1) : rr * (q + 1) + (xcd - rr) * q) + jj;
    const int c   = L / (NTILES * MBlk);
    const int rem = L - c * (NTILES * MBlk);
    const int mb  = rem / NTILES;
    const int nt  = rem - mb * NTILES;
    const int n0 = nt * BN;
    const int m0 = mb * BM;

    f32x4 acc[4][4];
#pragma unroll
    for (int i = 0; i < 4; ++i)
#pragma unroll
        for (int j = 0; j < 4; ++j) acc[i][j] = (f32x4)0.f;

    const int srow = tid >> 3;            // 0..31
    const int skq  = (tid & 7) << 2;      // 0,4,..,28 (halves)
    const int kgw  = skq >> 3;
    const int kjw  = skq & 7;
    const int kg   = lane >> 4;
    const int lrow = lane & 15;

    const unsigned short* bhp = WH + ((size_t)c * KBLKS * NTILES + nt) * WCHUNK;
    const unsigned short* bmp = WM + ((size_t)c * KBLKS * NTILES + nt) * WCHUNK;
    const float* xb = x + (size_t)m0 * 3 * KDIM + (size_t)c * KDIM + skq;

    float4 avn[4];
    f16x8 afh[4], afm[4], bfh[4], bfm[4];

    // ---- prologue: A[0] regs + B[0] DMA; split A[0]; A[1] in flight
    LOAD_A(0);                                         // vmcnt: 4
    DMA_B(0);                                          // vmcnt: 8
    asm volatile("s_waitcnt vmcnt(4)" ::: "memory");   // A[0] arrived
    __builtin_amdgcn_sched_barrier(0);
    SPLIT_A();                                         // A[0] -> LDS
    LOAD_A(1);                                         // vmcnt: 8 (B0 + A1)
    asm volatile("s_waitcnt vmcnt(4)" ::: "memory");   // B[0] landed (A1 flies)
    asm volatile("s_waitcnt lgkmcnt(0)" ::: "memory");
    __builtin_amdgcn_s_barrier();
    __builtin_amdgcn_sched_barrier(0);

    // ---- main loop, fully uniform (clamped tail indices)
    for (int kb = 0; kb < KBLKS; ++kb) {
        const int kn1 = (kb + 1 < KBLKS) ? kb + 1 : KBLKS - 1;
        const int kn2 = (kb + 2 < KBLKS) ? kb + 2 : KBLKS - 1;
        FRAGS();                                       // A[kb], B[kb] -> regs
        asm volatile("s_waitcnt lgkmcnt(0)" ::: "memory");
        __builtin_amdgcn_s_barrier();                  // all waves read LDS
        __builtin_amdgcn_sched_barrier(0);
        DMA_B(kn1);                                    // overwrite B buffer
        __builtin_amdgcn_sched_barrier(0);
        MFMA_CL();                                     // covers DMA latency
        __builtin_amdgcn_sched_barrier(0);
        SPLIT_A();                                     // avn = A[kb+1] -> LDS
        LOAD_A(kn2);                                   // next A into regs
        asm volatile("s_waitcnt vmcnt(4)" ::: "memory");  // B[kn1] done, A flies
        asm volatile("s_waitcnt lgkmcnt(0)" ::: "memory");
        __builtin_amdgcn_s_barrier();                  // publish A[kb+1], B[kn1]
        __builtin_amdgcn_sched_barrier(0);
    }

    // C layout: col = lane&15 (N), row = (lane>>4)*4 + reg (M)
#pragma unroll
    for (int ni = 0; ni < 4; ++ni) {
        int ncol = n0 + nbase + (ni << 4) + lrow;
        if (ncol >= NEFF) continue;
        int d = ncol / 200;
        int h = ncol - d * 200;
        float bias = bh[c * NEFF + ncol];
        size_t obase = (size_t)(c * 3 + d) * Mc;
#pragma unroll
        for (int mi = 0; mi < 4; ++mi) {
            int mrow = m0 + mbase + (mi << 4) + ((lane >> 4) << 2);
#pragma unroll
            for (int r = 0; r < 4; ++r)
                inj[(obase + mrow + r) * NH + h] = acc[mi][ni][r] + bias;
        }
    }
}

// K2: per-(b,h) thread owns 9 LIF cells; scan Tc steps, emit summed spikes z.
__global__ __launch_bounds__(256) void scan_z(
    const float* __restrict__ inj,  // [cd][t][j]
    float* __restrict__ z,          // [t][j]
    float* __restrict__ vhs, float* __restrict__ ihs,  // [cd][j]
    int Tc, int first)
{
    int j = blockIdx.x * 256 + threadIdx.x;
    float vh[9], ih[9];
    if (first) {
#pragma unroll
        for (int cd = 0; cd < 9; ++cd) { vh[cd] = 0.f; ih[cd] = 0.f; }
    } else {
#pragma unroll
        for (int cd = 0; cd < 9; ++cd) {
            vh[cd] = vhs[cd * NJ + j];
            ih[cd] = ihs[cd * NJ + j];
        }
    }
    float ivc[9], ivn[9];
#pragma unroll
    for (int cd = 0; cd < 9; ++cd)
        ivc[cd] = inj[(size_t)cd * Tc * NJ + j];
    if (Tc > 1) {
#pragma unroll
        for (int cd = 0; cd < 9; ++cd)
            ivn[cd] = inj[((size_t)cd * Tc + 1) * NJ + j];
    }
    for (int t = 0; t < Tc; ++t) {
        float zs = 0.f;
#pragma unroll
        for (int cd = 0; cd < 9; ++cd) {
            float iv = ivc[cd];
            ivc[cd] = ivn[cd];
            float vd = vh[cd] + 0.1f * (ih[cd] - vh[cd]);  // uses OLD ih
            ih[cd] = 0.8f * ih[cd] + iv;
            if (vd > 1.0f) { zs += 1.f; vh[cd] = 0.f; }
            else           { vh[cd] = vd; }
        }
        z[(size_t)t * NJ + j] = zs;
        if (t + 2 < Tc) {
#pragma unroll
            for (int cd = 0; cd < 9; ++cd)
                ivn[cd] = inj[((size_t)cd * Tc + t + 2) * NJ + j];
        }
    }
#pragma unroll
    for (int cd = 0; cd < 9; ++cd) {
        vhs[cd * NJ + j] = vh[cd];
        ihs[cd * NJ + j] = ih[cd];
    }
}

// K3: closed-form readout. vo[t] = 0.9^{dt+1} vo0 + (0.9^{dt+1}-0.8^{dt+1}) io0
//                                  + sum_s (0.9^{t-s}-0.8^{t-s}) u[s]
__global__ __launch_bounds__(256) void readout(
    const float* __restrict__ z,    // [t][j] chunk
    const float* __restrict__ Wo,   // [40][50]
    const float* __restrict__ bo,   // [40]
    float* __restrict__ out,        // [t][b][10]
    float* __restrict__ ios, float* __restrict__ vos,  // [b][40]
    int t0, int Tc, int first)
{
    const int b = blockIdx.x;
    const int tid = threadIdx.x;
    __shared__ float ush[TOTAL_T][40];
    __shared__ float usum[TOTAL_T][10];
    __shared__ float p9[TOTAL_T + 1], p8[TOTAL_T + 1];
    __shared__ float wsh[2000], bsh[40];
    for (int i = tid; i < 2000; i += 256) wsh[i] = Wo[i];
    if (tid < 40) bsh[tid] = bo[tid];
    if (tid == 0) {
        float a9 = 1.f, a8 = 1.f;
        for (int i = 0; i <= TOTAL_T; ++i) {
            p9[i] = a9; p8[i] = a8; a9 *= 0.9f; a8 *= 0.8f;
        }
    }
    __syncthreads();
    // phase 1: u[s][on] = bo + z . Wo
    for (int it = tid; it < Tc * 40; it += 256) {
        int s = it / 40, on = it - s * 40;
        int o = on / 10;
        const float* zr = z + (size_t)s * NJ + b * NH + o * 50;
        const float* wr = &wsh[on * 50];
        float dot = bsh[on];
#pragma unroll
        for (int k = 0; k < 50; ++k) dot += zr[k] * wr[k];
        ush[s][on] = dot;
    }
    __syncthreads();
    // phase 1.5: collapse o (readout is linear)
    for (int it = tid; it < Tc * 10; it += 256) {
        int s = it / 10, n = it - s * 10;
        usum[s][n] = ush[s][n] + ush[s][10 + n] + ush[s][20 + n] + ush[s][30 + n];
    }
    __syncthreads();
    // phase 2: out[t][n]
    for (int it = tid; it < Tc * 10; it += 256) {
        int t = it / 10, n = it - t * 10;
        float a = 0.f;
        for (int s = 0; s <= t; ++s)
            a += (p9[t - s] - p8[t - s]) * usum[s][n];
        if (!first) {
#pragma unroll
            for (int o = 0; o < 4; ++o) {
                int on = o * 10 + n;
                a += p9[t + 1] * vos[b * 40 + on]
                   + (p9[t + 1] - p8[t + 1]) * ios[b * 40 + on];
            }
        }
        out[((size_t)(t0 + t) * NB + b) * 10 + n] = a;
    }
    __syncthreads();
    // phase 3: analytic state handoff
    if (tid < 40) {
        int on = tid;
        float io0 = 0.f, vo0 = 0.f;
        if (!first) { io0 = ios[b * 40 + on]; vo0 = vos[b * 40 + on]; }
        float sio = 0.f, svo = 0.f;
        for (int s = 0; s < Tc; ++s) {
            sio += p8[Tc - 1 - s] * ush[s][on];
            svo += (p9[Tc - 1 - s] - p8[Tc - 1 - s]) * ush[s][on];
        }
        ios[b * 40 + on] = p8[Tc] * io0 + sio;
        vos[b * 40 + on] = p9[Tc] * vo0 + (p9[Tc] - p8[Tc]) * io0 + svo;
    }
}

extern "C" void kernel_launch(void* const* d_in, const int* in_sizes, int n_in,
                              void* d_out, int out_size, void* d_ws, size_t ws_size,
                              hipStream_t stream) {
    (void)in_sizes; (void)n_in; (void)out_size;
    const float* x  = (const float*)d_in[0];
    const float* Wh = (const float*)d_in[1];
    const float* bh = (const float*)d_in[2];
    const float* Wo = (const float*)d_in[3];
    const float* bo = (const float*)d_in[4];
    float* out = (float*)d_out;

    // ws layout: [vh][ih][io][vo][WH limbs][WM limbs][inj chunk][z chunk]
    float* vhs  = (float*)d_ws;          // 9*NJ
    float* ihs  = vhs + 9 * NJ;          // 9*NJ
    float* ios  = ihs + 9 * NJ;          // NB*40
    float* vos  = ios + NB * 40;         // NB*40
    unsigned short* WHl = (unsigned short*)(vos + NB * 40);
    unsigned short* WMl = WHl + NWHALF;
    float* inj  = (float*)(WMl + NWHALF);

    size_t fixed = ((size_t)9 * NJ * 2 + (size_t)NB * 40 * 2) * 4
                 + (size_t)NWHALF * 2 * 2;
    size_t per_t = (size_t)NB * (9 * NH * 4 + NH * 4);   // inj + z
    int Tc = 1;
    for (int t = TOTAL_T; t >= 1; --t) {
        if (fixed + (size_t)t * per_t <= ws_size) { Tc = t; break; }
    }

    presplit_wh<<<(3 * NPAD * KDIM + 255) / 256, 256, 0, stream>>>(Wh, WHl, WMl);

    for (int t0 = 0; t0 < TOTAL_T; t0 += Tc) {
        int tc = (TOTAL_T - t0 < Tc) ? (TOTAL_T - t0) : Tc;
        int Mc = tc * NB;
        int MBlk = Mc / BM;
        float* zbuf = inj + (size_t)9 * Mc * NH;
        gemm_inj_mfma<<<NTILES * MBlk * 3, 256, 0, stream>>>(
            x + (size_t)t0 * NB * 3 * KDIM, WHl, WMl, bh, inj, Mc, MBlk);
        scan_z<<<NJ / 256, 256, 0, stream>>>(inj, zbuf, vhs, ihs, tc, t0 == 0);
        readout<<<NB, 256, 0, stream>>>(
            zbuf, Wo, bo, out, ios, vos, t0, tc, t0 == 0);
    }
}

// Round 13
// 426.789 us; speedup vs baseline: 4.1220x; 1.0720x over previous
//
#include <hip/hip_runtime.h>
#include <stdint.h>

// Problem constants
#define TOTAL_T 100
#define NB 256          // batch
#define NH 200          // hidden per (c,d) cell
#define NCD 9           // C*D
#define NJ (NB*NH)      // 51200
#define KDIM 1024       // FS*FS
#define NEFF 600        // d*200+h per c
#define NPAD 640        // 5 tiles of 128
#define NTILES 5
#define KBLKS 32        // KDIM/32

// GEMM tiling
#define BM 128
#define BN 128
#define BK 32
#define AST 1040        // A kg-subtile stride in halves (128*8 + 8 pad)

// Pre-split Wh limb array: [c][kb][nt][kg][row][8] halves, 4096 halves per (c,kb,nt) chunk
#define WCHUNK 4096
#define NWHALF (3 * KBLKS * NTILES * WCHUNK)

typedef _Float16 f16x8 __attribute__((ext_vector_type(8)));
typedef float    f32x4 __attribute__((ext_vector_type(4)));
typedef __attribute__((address_space(3))) uint32_t as3_u32;
typedef __attribute__((address_space(1))) uint32_t as1_u32;

// ---------------- P2: pre-split Wh into fp16 hi/mid limbs, tiled layout ---------
__global__ __launch_bounds__(256) void presplit_wh(
    const float* __restrict__ Wh, unsigned short* __restrict__ WH,
    unsigned short* __restrict__ WM)
{
    int idx = blockIdx.x * 256 + threadIdx.x;      // over 3*640*1024
    if (idx >= 3 * NPAD * KDIM) return;
    int k = idx & (KDIM - 1);
    int n = (idx >> 10) % NPAD;
    int c = idx / (NPAD * KDIM);
    float v = 0.f;
    if (n < NEFF) v = Wh[((size_t)c * NEFF + n) * KDIM + k];
    _Float16 h = (_Float16)v;                      // RN
    float r = v - (float)h;                        // exact
    _Float16 m = (_Float16)r;                      // RN
    int kb = k >> 5, kg = (k >> 3) & 3, kj = k & 7;
    int nt = n >> 7, row = n & 127;
    size_t off = (((size_t)c * KBLKS + kb) * NTILES + nt) * WCHUNK
               + (kg * 128 + row) * 8 + kj;
    WH[off] = __builtin_bit_cast(unsigned short, h);
    WM[off] = __builtin_bit_cast(unsigned short, m);
}

// ---------------- K1: fp16 2-limb 3-product MFMA GEMM, phased K-step ------------
__global__ __launch_bounds__(256, 3) void gemm_inj_mfma(
    const float* __restrict__ x,          // chunk base
    const unsigned short* __restrict__ WH,
    const unsigned short* __restrict__ WM,
    const float* __restrict__ bh,
    float* __restrict__ inj,
    int Mc, int MBlk)                     // MBlk = Mc/128
{
    __shared__ __align__(16) unsigned short Ah[4 * AST], Am[4 * AST];       // ~16.6 KB
    __shared__ __align__(16) unsigned short Bh[2][4096], Bm[2][4096];       // 32 KB

    const int tid  = threadIdx.x;
    const int lane = tid & 63;
    const int w    = tid >> 6;            // 4 waves, 2x2
    const int mbase = (w >> 1) * 64;
    const int nbase = (w & 1) * 64;

    // XCD-aware bijective remap: hw id -> logical (c, mb, nt), nt fastest.
    const int nblk = gridDim.x;
    const int hw   = blockIdx.x;
    const int xcd  = hw & 7, jj = hw >> 3;
    const int q = nblk >> 3, rr = nblk & 7;
    const int L = (xcd < rr ? xcd * (q + 1) : rr * (q + 1) + (xcd - rr) * q) + jj;
    const int c   = L / (NTILES * MBlk);
    const int rem = L - c * (NTILES * MBlk);
    const int mb  = rem / NTILES;
    const int nt  = rem - mb * NTILES;
    const int n0 = nt * BN;
    const int m0 = mb * BM;

    f32x4 acc[4][4];
#pragma unroll
    for (int i = 0; i < 4; ++i)
#pragma unroll
        for (int j = 0; j < 4; ++j) acc[i][j] = (f32x4)0.f;

    const int srow = tid >> 3;            // 0..31
    const int skq  = (tid & 7) << 2;      // 0,4,..,28 (halves)
    const int kgw  = skq >> 3;            // write subtile
    const int kjw  = skq & 7;             // 0 or 4

    const unsigned short* bhp = WH + ((size_t)c * KBLKS * NTILES + nt) * WCHUNK;
    const unsigned short* bmp = WM + ((size_t)c * KBLKS * NTILES + nt) * WCHUNK;
    const float* xb = x + (size_t)m0 * 3 * KDIM + (size_t)c * KDIM + skq;

    float4 av[4];
    // ---- prologue: A[0] -> regs, B[0] -> buf 0
#pragma unroll
    for (int l = 0; l < 4; ++l)
        av[l] = *reinterpret_cast<const float4*>(xb + (size_t)(srow + (l << 5)) * 3 * KDIM);
#pragma unroll
    for (int i = 0; i < 2; ++i) {
        int seg = (i << 2) + w;
        __builtin_amdgcn_global_load_lds(
            (const as1_u32*)(bhp + ((seg << 6) + lane) * 8),
            (as3_u32*)&Bh[0][seg << 9], 16, 0, 0);
        __builtin_amdgcn_global_load_lds(
            (const as1_u32*)(bmp + ((seg << 6) + lane) * 8),
            (as3_u32*)&Bm[0][seg << 9], 16, 0, 0);
    }
    __syncthreads();                      // B[0] in LDS, av = A[0]

    // split A[0] -> LDS (subtiled layout)
#pragma unroll
    for (int l = 0; l < 4; ++l) {
        int row = srow + (l << 5);
        float a[4] = {av[l].x, av[l].y, av[l].z, av[l].w};
        uint32_t hw2[2], mw2[2];
#pragma unroll
        for (int p = 0; p < 2; ++p) {
            _Float16 h0 = (_Float16)a[2 * p];
            _Float16 h1 = (_Float16)a[2 * p + 1];
            float r0 = a[2 * p] - (float)h0;
            float r1 = a[2 * p + 1] - (float)h1;
            _Float16 m0v = (_Float16)r0;
            _Float16 m1v = (_Float16)r1;
            hw2[p] = (uint32_t)__builtin_bit_cast(unsigned short, h0)
                   | ((uint32_t)__builtin_bit_cast(unsigned short, h1) << 16);
            mw2[p] = (uint32_t)__builtin_bit_cast(unsigned short, m0v)
                   | ((uint32_t)__builtin_bit_cast(unsigned short, m1v) << 16);
        }
        int off = kgw * AST + row * 8 + kjw;
        *reinterpret_cast<uint2*>(&Ah[off]) = make_uint2(hw2[0], hw2[1]);
        *reinterpret_cast<uint2*>(&Am[off]) = make_uint2(mw2[0], mw2[1]);
    }
    __syncthreads();                      // A[0] visible

    const int kg   = lane >> 4;
    const int lrow = lane & 15;

    int cur = 0;
    for (int kb = 0; kb < KBLKS; ++kb) {
        const bool more = (kb + 1 < KBLKS);
        // ---- issue next-tile global loads FIRST (vmcnt; drained at end barrier)
        if (more) {
#pragma unroll
            for (int l = 0; l < 4; ++l)
                av[l] = *reinterpret_cast<const float4*>(
                    xb + (size_t)(srow + (l << 5)) * 3 * KDIM + ((kb + 1) << 5));
            const unsigned short* nbh = bhp + (size_t)(kb + 1) * NTILES * WCHUNK;
            const unsigned short* nbm = bmp + (size_t)(kb + 1) * NTILES * WCHUNK;
            int nb_ = cur ^ 1;
#pragma unroll
            for (int i = 0; i < 2; ++i) {
                int seg = (i << 2) + w;
                __builtin_amdgcn_global_load_lds(
                    (const as1_u32*)(nbh + ((seg << 6) + lane) * 8),
                    (as3_u32*)&Bh[nb_][seg << 9], 16, 0, 0);
                __builtin_amdgcn_global_load_lds(
                    (const as1_u32*)(nbm + ((seg << 6) + lane) * 8),
                    (as3_u32*)&Bm[nb_][seg << 9], 16, 0, 0);
            }
        }

        // ---- A frag reads (8 b128), pinned before B reads
        f16x8 afh[4], afm[4], bfh[4], bfm[4];
#pragma unroll
        for (int mi = 0; mi < 4; ++mi) {
            int off = kg * AST + (mbase + (mi << 4) + lrow) * 8;
            afh[mi] = *reinterpret_cast<const f16x8*>(&Ah[off]);
            afm[mi] = *reinterpret_cast<const f16x8*>(&Am[off]);
        }
        __builtin_amdgcn_sched_barrier(0);
        // ---- B0, B1 frag reads
#pragma unroll
        for (int ni = 0; ni < 2; ++ni) {
            int boff = ((kg << 7) + nbase + (ni << 4) + lrow) << 3;
            bfh[ni] = *reinterpret_cast<const f16x8*>(&Bh[cur][boff]);
            bfm[ni] = *reinterpret_cast<const f16x8*>(&Bm[cur][boff]);
        }
        __builtin_amdgcn_sched_barrier(0);
        asm volatile("s_waitcnt lgkmcnt(4)" ::: "memory");  // A frags complete
        __builtin_amdgcn_sched_barrier(0);
        __builtin_amdgcn_s_barrier();     // raw: A reads done; vmcnt prefetch lives on
        __builtin_amdgcn_sched_barrier(0);

        __builtin_amdgcn_s_setprio(1);
        // ---- phase 0: issue B2; wait B0; MFMA ni=0
        {
            int boff = ((kg << 7) + nbase + (2 << 4) + lrow) << 3;
            bfh[2] = *reinterpret_cast<const f16x8*>(&Bh[cur][boff]);
            bfm[2] = *reinterpret_cast<const f16x8*>(&Bm[cur][boff]);
        }
        asm volatile("s_waitcnt lgkmcnt(4)" ::: "memory");
        __builtin_amdgcn_sched_barrier(0);
#pragma unroll
        for (int mi = 0; mi < 4; ++mi) {
            f32x4 a = acc[mi][0];
            a = __builtin_amdgcn_mfma_f32_16x16x32_f16(afh[mi], bfh[0], a, 0, 0, 0);
            a = __builtin_amdgcn_mfma_f32_16x16x32_f16(afh[mi], bfm[0], a, 0, 0, 0);
            a = __builtin_amdgcn_mfma_f32_16x16x32_f16(afm[mi], bfh[0], a, 0, 0, 0);
            acc[mi][0] = a;
        }
        __builtin_amdgcn_sched_barrier(0);
        // ---- phase 1: issue B3; wait B1; MFMA ni=1
        {
            int boff = ((kg << 7) + nbase + (3 << 4) + lrow) << 3;
            bfh[3] = *reinterpret_cast<const f16x8*>(&Bh[cur][boff]);
            bfm[3] = *reinterpret_cast<const f16x8*>(&Bm[cur][boff]);
        }
        asm volatile("s_waitcnt lgkmcnt(4)" ::: "memory");
        __builtin_amdgcn_sched_barrier(0);
#pragma unroll
        for (int mi = 0; mi < 4; ++mi) {
            f32x4 a = acc[mi][1];
            a = __builtin_amdgcn_mfma_f32_16x16x32_f16(afh[mi], bfh[1], a, 0, 0, 0);
            a = __builtin_amdgcn_mfma_f32_16x16x32_f16(afh[mi], bfm[1], a, 0, 0, 0);
            a = __builtin_amdgcn_mfma_f32_16x16x32_f16(afm[mi], bfh[1], a, 0, 0, 0);
            acc[mi][1] = a;
        }
        __builtin_amdgcn_sched_barrier(0);
        // ---- phase 2: wait B2; MFMA ni=2
        asm volatile("s_waitcnt lgkmcnt(2)" ::: "memory");
        __builtin_amdgcn_sched_barrier(0);
#pragma unroll
        for (int mi = 0; mi < 4; ++mi) {
            f32x4 a = acc[mi][2];
            a = __builtin_amdgcn_mfma_f32_16x16x32_f16(afh[mi], bfh[2], a, 0, 0, 0);
            a = __builtin_amdgcn_mfma_f32_16x16x32_f16(afh[mi], bfm[2], a, 0, 0, 0);
            a = __builtin_amdgcn_mfma_f32_16x16x32_f16(afm[mi], bfh[2], a, 0, 0, 0);
            acc[mi][2] = a;
        }
        __builtin_amdgcn_sched_barrier(0);
        // ---- phase 3: wait B3; MFMA ni=3
        asm volatile("s_waitcnt lgkmcnt(0)" ::: "memory");
        __builtin_amdgcn_sched_barrier(0);
#pragma unroll
        for (int mi = 0; mi < 4; ++mi) {
            f32x4 a = acc[mi][3];
            a = __builtin_amdgcn_mfma_f32_16x16x32_f16(afh[mi], bfh[3], a, 0, 0, 0);
            a = __builtin_amdgcn_mfma_f32_16x16x32_f16(afh[mi], bfm[3], a, 0, 0, 0);
            a = __builtin_amdgcn_mfma_f32_16x16x32_f16(afm[mi], bfh[3], a, 0, 0, 0);
            acc[mi][3] = a;
        }
        __builtin_amdgcn_s_setprio(0);
        __builtin_amdgcn_sched_barrier(0);

        // ---- split A[kb+1] (regs arrived during MFMA) -> LDS
        if (more) {
#pragma unroll
            for (int l = 0; l < 4; ++l) {
                int row = srow + (l << 5);
                float a[4] = {av[l].x, av[l].y, av[l].z, av[l].w};
                uint32_t hw2[2], mw2[2];
#pragma unroll
                for (int p = 0; p < 2; ++p) {
                    _Float16 h0 = (_Float16)a[2 * p];
                    _Float16 h1 = (_Float16)a[2 * p + 1];
                    float r0 = a[2 * p] - (float)h0;
                    float r1 = a[2 * p + 1] - (float)h1;
                    _Float16 m0v = (_Float16)r0;
                    _Float16 m1v = (_Float16)r1;
                    hw2[p] = (uint32_t)__builtin_bit_cast(unsigned short, h0)
                           | ((uint32_t)__builtin_bit_cast(unsigned short, h1) << 16);
                    mw2[p] = (uint32_t)__builtin_bit_cast(unsigned short, m0v)
                           | ((uint32_t)__builtin_bit_cast(unsigned short, m1v) << 16);
                }
                int off = kgw * AST + row * 8 + kjw;
                *reinterpret_cast<uint2*>(&Ah[off]) = make_uint2(hw2[0], hw2[1]);
                *reinterpret_cast<uint2*>(&Am[off]) = make_uint2(mw2[0], mw2[1]);
            }
        }
        __syncthreads();                  // drains vmcnt (B[kb+1] ready) + lgkm (A writes)
        cur ^= 1;
    }

    // C layout: col = lane&15 (N), row = (lane>>4)*4 + reg (M)
#pragma unroll
    for (int ni = 0; ni < 4; ++ni) {
        int ncol = n0 + nbase + (ni << 4) + (lane & 15);
        if (ncol >= NEFF) continue;
        int d = ncol / 200;
        int h = ncol - d * 200;
        float bias = bh[c * NEFF + ncol];
        size_t obase = (size_t)(c * 3 + d) * Mc;
#pragma unroll
        for (int mi = 0; mi < 4; ++mi) {
            int mrow = m0 + mbase + (mi << 4) + ((lane >> 4) << 2);
#pragma unroll
            for (int r = 0; r < 4; ++r)
                inj[(obase + mrow + r) * NH + h] = acc[mi][ni][r] + bias;
        }
    }
}

// K2: fused per-batch scan: LIF neurons + readout dots + output integrators.
// One block per b; z and u never leave LDS.
__global__ __launch_bounds__(256) void scan_fused(
    const float* __restrict__ inj,  // [cd][t][b][h]
    const float* __restrict__ Wo,   // [40][50]
    const float* __restrict__ bo,   // [40]
    float* __restrict__ out,        // [t][b][10]
    float* __restrict__ vhs, float* __restrict__ ihs,   // [cd][j]
    float* __restrict__ ios, float* __restrict__ vos,   // [b][40]
    int t0, int Tc, int first)
{
    const int b = blockIdx.x;
    const int tid = threadIdx.x;
    __shared__ float zsh[NH];
    __shared__ float vsh[40];
    __shared__ float wsh[2000];
    __shared__ float bsh[40];

    for (int i = tid; i < 2000; i += 256) wsh[i] = Wo[i];
    if (tid < 40) bsh[tid] = bo[tid];

    const int j = b * NH + tid;
    float vh[9], ih[9];
    if (tid < NH) {
        if (first) {
#pragma unroll
            for (int cd = 0; cd < 9; ++cd) { vh[cd] = 0.f; ih[cd] = 0.f; }
        } else {
#pragma unroll
            for (int cd = 0; cd < 9; ++cd) {
                vh[cd] = vhs[cd * NJ + j];
                ih[cd] = ihs[cd * NJ + j];
            }
        }
    }
    float rio = 0.f, rvo = 0.f;
    if (tid < 40 && !first) { rio = ios[b * 40 + tid]; rvo = vos[b * 40 + tid]; }

    // depth-2 inj prefetch
    float ivc[9], ivn[9];
    if (tid < NH) {
#pragma unroll
        for (int cd = 0; cd < 9; ++cd)
            ivc[cd] = inj[((size_t)cd * Tc + 0) * NJ + j];
        if (Tc > 1) {
#pragma unroll
            for (int cd = 0; cd < 9; ++cd)
                ivn[cd] = inj[((size_t)cd * Tc + 1) * NJ + j];
        }
    }
    __syncthreads();   // wsh/bsh ready

    for (int t = 0; t < Tc; ++t) {
        // phase A: LIF step, spike sum -> zsh; rotate prefetch
        if (tid < NH) {
            float zs = 0.f;
#pragma unroll
            for (int cd = 0; cd < 9; ++cd) {
                float iv = ivc[cd];
                ivc[cd] = ivn[cd];
                float vd = vh[cd] + 0.1f * (ih[cd] - vh[cd]);  // OLD ih
                ih[cd] = 0.8f * ih[cd] + iv;
                if (vd > 1.0f) { zs += 1.f; vh[cd] = 0.f; }
                else           { vh[cd] = vd; }
            }
            zsh[tid] = zs;
            if (t + 2 < Tc) {
#pragma unroll
                for (int cd = 0; cd < 9; ++cd)
                    ivn[cd] = inj[((size_t)cd * Tc + t + 2) * NJ + j];
            }
        }
        __syncthreads();
        // phase B: 40 readout integrators
        if (tid < 40) {
            int o = tid / 10;
            float dot = bsh[tid];
            const float* wr = &wsh[tid * 50];
            const float* zr = &zsh[o * 50];
#pragma unroll
            for (int k = 0; k < 50; ++k) dot += zr[k] * wr[k];
            rvo = rvo + 0.1f * (rio - rvo);   // old io
            rio = 0.8f * rio + dot;
            vsh[tid] = rvo;
        }
        __syncthreads();
        // phase C: 10 output writes (vsh stable until next phase B)
        if (tid < 10)
            out[((size_t)(t0 + t) * NB + b) * 10 + tid] =
                vsh[tid] + vsh[10 + tid] + vsh[20 + tid] + vsh[30 + tid];
    }

    if (tid < NH) {
#pragma unroll
        for (int cd = 0; cd < 9; ++cd) {
            vhs[cd * NJ + j] = vh[cd];
            ihs[cd * NJ + j] = ih[cd];
        }
    }
    if (tid < 40) { ios[b * 40 + tid] = rio; vos[b * 40 + tid] = rvo; }
}

extern "C" void kernel_launch(void* const* d_in, const int* in_sizes, int n_in,
                              void* d_out, int out_size, void* d_ws, size_t ws_size,
                              hipStream_t stream) {
    (void)in_sizes; (void)n_in; (void)out_size;
    const float* x  = (const float*)d_in[0];
    const float* Wh = (const float*)d_in[1];
    const float* bh = (const float*)d_in[2];
    const float* Wo = (const float*)d_in[3];
    const float* bo = (const float*)d_in[4];
    float* out = (float*)d_out;

    // ws layout: [vh][ih][io][vo][WH limbs][WM limbs][inj chunk]
    float* vhs  = (float*)d_ws;          // 9*NJ
    float* ihs  = vhs + 9 * NJ;          // 9*NJ
    float* ios  = ihs + 9 * NJ;          // NB*40
    float* vos  = ios + NB * 40;         // NB*40
    unsigned short* WHl = (unsigned short*)(vos + NB * 40);
    unsigned short* WMl = WHl + NWHALF;
    float* inj  = (float*)(WMl + NWHALF);

    size_t fixed = ((size_t)9 * NJ * 2 + (size_t)NB * 40 * 2) * 4
                 + (size_t)NWHALF * 2 * 2;
    size_t per_t = (size_t)NB * 9 * NH * 4;   // inj only (z, u live in LDS)
    int Tc = 1;
    for (int t = TOTAL_T; t >= 1; --t) {
        if (fixed + (size_t)t * per_t <= ws_size) { Tc = t; break; }
    }

    presplit_wh<<<(3 * NPAD * KDIM + 255) / 256, 256, 0, stream>>>(Wh, WHl, WMl);

    for (int t0 = 0; t0 < TOTAL_T; t0 += Tc) {
        int tc = (TOTAL_T - t0 < Tc) ? (TOTAL_T - t0) : Tc;
        int Mc = tc * NB;
        int MBlk = Mc / BM;
        gemm_inj_mfma<<<NTILES * MBlk * 3, 256, 0, stream>>>(
            x + (size_t)t0 * NB * 3 * KDIM, WHl, WMl, bh, inj, Mc, MBlk);
        scan_fused<<<NB, 256, 0, stream>>>(
            inj, Wo, bo, out, vhs, ihs, ios, vos, t0, tc, t0 == 0);
    }
}